// Round 5
// baseline (826.728 us; speedup 1.0000x reference)
//
#include <hip/hip_runtime.h>
#include <math.h>

#define FDIM   128
#define TWOF   256
#define NRBF_  20
#define INDIM  276
#define K1PAD  288          // INDIM padded to multiple of 32
#define TE     64           // edges per workgroup (proven best: 4 blocks/CU)

typedef __bf16 bf16x8 __attribute__((ext_vector_type(8)));
typedef float  f32x4  __attribute__((ext_vector_type(4)));
typedef float  f32x2  __attribute__((ext_vector_type(2)));
typedef unsigned int u32x4v __attribute__((ext_vector_type(4)));

__device__ inline float blo(unsigned p){ return __uint_as_float(p << 16); }
__device__ inline float bhi(unsigned p){ return __uint_as_float(p & 0xffff0000u); }

// async global->LDS, 16B per lane, dest = lds base + laneId*16 (linear)
__device__ __forceinline__ void gload_lds16(const void* g, void* l) {
    __builtin_amdgcn_global_load_lds(
        (const __attribute__((address_space(1))) unsigned int*)g,
        (__attribute__((address_space(3))) unsigned int*)l, 16, 0, 0);
}

// ---------------- helper kernels ----------------

__global__ void sniff_idx(const int* __restrict__ ei, int nsample, int* __restrict__ flag) {
    __shared__ int any;
    if (threadIdx.x == 0) any = 0;
    __syncthreads();
    int nz = 0;
    for (int i = threadIdx.x; i < nsample; i += blockDim.x)
        nz |= (ei[2 * i + 1] != 0);
    if (nz) atomicOr(&any, 1);
    __syncthreads();
    if (threadIdx.x == 0) *flag = any;
}

__global__ void init_out(const float4* __restrict__ s4, const float4* __restrict__ v4,
                         float4* __restrict__ out4, int nf4, int total4) {
    for (int i = blockIdx.x * blockDim.x + threadIdx.x; i < total4;
         i += gridDim.x * blockDim.x)
        out4[i] = (i < nf4) ? s4[i] : v4[i - nf4];
}

__global__ void prep_weights(const float* __restrict__ W1, const float* __restrict__ W2,
                             const float* __restrict__ Ws, const float* __restrict__ Wv,
                             __bf16* __restrict__ W1t, __bf16* __restrict__ W2t,
                             __bf16* __restrict__ W3t) {
    int id = blockIdx.x * 256 + threadIdx.x;
    const int n1 = 256 * K1PAD;
    if (id < n1) {
        int n = id / K1PAD, k = id - n * K1PAD;
        W1t[id] = (k < INDIM) ? (__bf16)W1[k * TWOF + n] : (__bf16)0.f;
    } else if (id < n1 + 65536) {
        int j = id - n1; int n = j >> 8, k = j & 255;
        W2t[j] = (__bf16)W2[k * TWOF + n];
    } else if (id < n1 + 131072) {
        int j = id - n1 - 65536; int n = j >> 8, k = j & 255;
        W3t[j] = (n < FDIM) ? (__bf16)Ws[k * FDIM + n]
                            : (__bf16)Wv[k * FDIM + (n - FDIM)];
    }
}

// pre-convert s (N x 128 f32) -> bf16 once: halves gather traffic, removes cvt from hot loop
__global__ void prep_s(const float4* __restrict__ s4, bf16x8* __restrict__ s16, int n8) {
    int i = blockIdx.x * 256 + threadIdx.x;
    if (i >= n8) return;
    float4 a = s4[i * 2], b = s4[i * 2 + 1];
    bf16x8 o;
    o[0] = (__bf16)a.x; o[1] = (__bf16)a.y; o[2] = (__bf16)a.z; o[3] = (__bf16)a.w;
    o[4] = (__bf16)b.x; o[5] = (__bf16)b.y; o[6] = (__bf16)b.z; o[7] = (__bf16)b.w;
    s16[i] = o;
}

// ---------------- CSR build ----------------

__global__ void zero_hist(int* __restrict__ hist, int N) {
    int i = blockIdx.x * 256 + threadIdx.x;
    if (i < N) hist[i] = 0;
}

__global__ void hist_k(const int* __restrict__ ei, const int* __restrict__ flag,
                       int* __restrict__ hist, int E) {
    int e = blockIdx.x * 256 + threadIdx.x;
    if (e >= E) return;
    int dst = (*flag == 0) ? ei[2 * (E + e)] : ei[E + e];
    atomicAdd(&hist[dst], 1);
}

__global__ void scan_a(const int* __restrict__ hist, int* __restrict__ loc,
                       int* __restrict__ bsum, int N) {
    __shared__ int sums[256];
    int t = threadIdx.x;
    int base = blockIdx.x * 1024 + t * 4;
    int v0 = (base + 0 < N) ? hist[base + 0] : 0;
    int v1 = (base + 1 < N) ? hist[base + 1] : 0;
    int v2 = (base + 2 < N) ? hist[base + 2] : 0;
    int v3 = (base + 3 < N) ? hist[base + 3] : 0;
    int s = v0 + v1 + v2 + v3;
    sums[t] = s;
    __syncthreads();
    for (int off = 1; off < 256; off <<= 1) {
        int x = (t >= off) ? sums[t - off] : 0;
        __syncthreads();
        sums[t] += x;
        __syncthreads();
    }
    int excl = sums[t] - s;
    if (t == 255) bsum[blockIdx.x] = sums[255];
    if (base + 0 < N) loc[base + 0] = excl; excl += v0;
    if (base + 1 < N) loc[base + 1] = excl; excl += v1;
    if (base + 2 < N) loc[base + 2] = excl; excl += v2;
    if (base + 3 < N) loc[base + 3] = excl;
}

__global__ void scan_b(int* __restrict__ bsum, int nb) {
    if (threadIdx.x == 0 && blockIdx.x == 0) {
        int run = 0;
        for (int i = 0; i < nb; ++i) { int v = bsum[i]; bsum[i] = run; run += v; }
    }
}

__global__ void scan_c(const int* __restrict__ loc, const int* __restrict__ bsum,
                       int* __restrict__ rs, int* __restrict__ cursor, int N, int E) {
    int i = blockIdx.x * 256 + threadIdx.x;
    if (i < N) {
        int v = loc[i] + bsum[i >> 10];
        rs[i] = v; cursor[i] = v;
    }
    if (i == 0) rs[N] = E;
}

// store edge -> CSR slot (perm), not slot -> edge
__global__ void scatter_k(const int* __restrict__ ei, const int* __restrict__ flag,
                          int* __restrict__ cursor, int* __restrict__ perm, int E) {
    int e = blockIdx.x * 256 + threadIdx.x;
    if (e >= E) return;
    int dst = (*flag == 0) ? ei[2 * (E + e)] : ei[E + e];
    int pos = atomicAdd(&cursor[dst], 1);
    perm[e] = pos;
}

// ---------------- main edge kernel ----------------
// Xs[64][256] bf16, dense 512B rows, XOR-swizzled (16B slot ^ (row&7)):
//   - filled by global_load_lds DMA (1KB per full-wave instr, source pre-swizzled)
//   - L1 X, then H (L1/L2 output), then EO staging all live here
// Rb[64][40]: RBF cols 256..287 (80B stride: 16B-aligned, ~2-way banks)
// DMA gather is independent of Phase A -> single merged barrier; zero VGPR staging.

template<int CSR>
__launch_bounds__(256, 4)
__global__ void edge_kernel(const __bf16* __restrict__ s16,
                            const float* __restrict__ pos,
                            const int* __restrict__ ei,
                            const float* __restrict__ b1, const float* __restrict__ b2,
                            const float* __restrict__ bsm, const float* __restrict__ bvm,
                            const float* __restrict__ centers, const float* __restrict__ widths,
                            const __bf16* __restrict__ W1t, const __bf16* __restrict__ W2t,
                            const __bf16* __restrict__ W3t,
                            const int* __restrict__ flag,
                            const int* __restrict__ perm,
                            __bf16* __restrict__ EO,
                            float* __restrict__ dirx, float* __restrict__ diry,
                            float* __restrict__ dirz,
                            float* __restrict__ out, int N, int E) {
    __shared__ __align__(1024) __bf16 Xs[TE][256];
    __shared__ __align__(16)   __bf16 Rb[TE][40];
    __shared__ float sdir[3][TE];
    __shared__ int ssrc[TE], sdst[TE], svalid[TE], sperm[TE];

    const int t    = threadIdx.x;
    const int lane = t & 63;
    const int wave = t >> 6;
    const int e0   = blockIdx.x * TE;
    const int i64  = (*flag == 0);

    // ---- DMA gather: each wave issues 8 x 1KB global_load_lds (2 edge-rows each).
    // LDS dest is linear (base + lane*16); swizzle achieved by pre-swizzling the
    // per-lane GLOBAL chunk index: slot j of row e holds source chunk j^(e&7).
    {
        const int j    = lane & 31;       // 16B slot within the 512B edge-row
        const int rsel = lane >> 5;       // which of the 2 rows this instr covers
        int nd[8];
#pragma unroll
        for (int i = 0; i < 8; ++i) {
            int eg = e0 + wave * 16 + 2 * i + rsel;
            if (eg >= E) eg = E - 1;                    // clamp: garbage rows masked by svalid
            int idx = (j < 16) ? eg : (E + eg);         // src half : dst half
            nd[i] = i64 ? ei[2 * idx] : ei[idx];
        }
#pragma unroll
        for (int i = 0; i < 8; ++i) {
            int q = (j & 15) ^ ((2 * i + rsel) & 7);    // pre-swizzled source chunk
            const char* gp = (const char*)s16 + ((size_t)(unsigned)nd[i] << 8) + (q << 4);
            char* lp = (char*)&Xs[wave * 16 + 2 * i][0];
            gload_lds16(gp, lp);
        }
    }

    // ---- Phase A: per-edge prep, 4 threads per edge (overlaps DMA latency)
    {
        const int eL  = t >> 2;      // 0..63 local edge
        const int sub = t & 3;       // 0..3 RBF slice
        int e = e0 + eL;
        int valid = (e < E);
        int srcn = 0, dstn = 0;
        if (valid) {
            if (i64) { srcn = ei[2 * e]; dstn = ei[2 * (E + e)]; }
            else     { srcn = ei[e];     dstn = ei[E + e]; }
        }
        float rx = pos[dstn * 3 + 0] - pos[srcn * 3 + 0];
        float ry = pos[dstn * 3 + 1] - pos[srcn * 3 + 1];
        float rz = pos[dstn * 3 + 2] - pos[srcn * 3 + 2];
        float dist = sqrtf(rx * rx + ry * ry + rz * rz);
        if (sub == 0) {
            ssrc[eL] = srcn; sdst[eL] = dstn; svalid[eL] = valid;
            float inv = dist > 0.f ? 1.f / dist : 0.f;
            float dx = rx * inv, dy = ry * inv, dz = rz * inv;
            sdir[0][eL] = dx; sdir[1][eL] = dy; sdir[2][eL] = dz;
            int p = 0;
            if (CSR && valid) {
                p = perm[e];
                __builtin_nontemporal_store(dx, &dirx[p]);
                __builtin_nontemporal_store(dy, &diry[p]);
                __builtin_nontemporal_store(dz, &dirz[p]);
            }
            sperm[eL] = p;
        }
#pragma unroll
        for (int k8 = 0; k8 < 8; ++k8) {
            int k = sub * 8 + k8;
            float val = 0.f;
            if (k < NRBF_) {
                float u = (dist - centers[k]) / (widths[k] + 1e-8f);
                val = __expf(-u * u);
            }
            Rb[eL][k] = (__bf16)val;
        }
    }
    __syncthreads();    // drains DMA (vmcnt 0) + Phase A LDS

    const int l15 = lane & 15;
    const int kg  = (lane >> 4) * 8;
    const int nbase = wave * 64;
    const unsigned axor = (unsigned)((l15 & 7) << 4);        // A-read swizzle (row&7 == l15&7)
    const char* xb = (const char*)&Xs[0][0] + l15 * 512;     // + et*8192 folded into ds offsets
    char* xw = (char*)&Xs[0][0];

    f32x4 acc[4][4];

    // ================= Layer 1: K=288 (reads swizzled X + Rb) =================
#pragma unroll
    for (int et = 0; et < 4; ++et)
#pragma unroll
        for (int nt = 0; nt < 4; ++nt) acc[et][nt] = (f32x4)0.f;
    {
        const __bf16* bp[4];
#pragma unroll
        for (int nt = 0; nt < 4; ++nt)
            bp[nt] = &W1t[(size_t)(nbase + nt * 16 + l15) * K1PAD + kg];
        bf16x8 bcur[4];
#pragma unroll
        for (int nt = 0; nt < 4; ++nt) bcur[nt] = *(const bf16x8*)bp[nt];
        __builtin_amdgcn_s_setprio(1);
#pragma unroll
        for (int kc = 0; kc < K1PAD; kc += 32) {
            bf16x8 bnxt[4];
            if (kc + 32 < K1PAD) {
#pragma unroll
                for (int nt = 0; nt < 4; ++nt)
                    bnxt[nt] = *(const bf16x8*)(bp[nt] + kc + 32);
            }
            bf16x8 a[4];
            if (kc < 256) {
#pragma unroll
                for (int et = 0; et < 4; ++et)
                    a[et] = *(const bf16x8*)(xb + et * 8192 + (((unsigned)((kc + kg) * 2)) ^ axor));
            } else {
#pragma unroll
                for (int et = 0; et < 4; ++et)
                    a[et] = *(const bf16x8*)&Rb[et * 16 + l15][kg];
            }
#pragma unroll
            for (int nt = 0; nt < 4; ++nt)
#pragma unroll
                for (int et = 0; et < 4; ++et)
                    acc[et][nt] = __builtin_amdgcn_mfma_f32_16x16x32_bf16(a[et], bcur[nt], acc[et][nt], 0, 0, 0);
#pragma unroll
            for (int nt = 0; nt < 4; ++nt) bcur[nt] = bnxt[nt];
        }
        __builtin_amdgcn_s_setprio(0);
    }
    __syncthreads();   // all X reads complete before H overwrites the buffer
#pragma unroll
    for (int nt = 0; nt < 4; ++nt) {
        int n = nbase + nt * 16 + l15;
        float bb = b1[n];
#pragma unroll
        for (int et = 0; et < 4; ++et)
#pragma unroll
            for (int r = 0; r < 4; ++r) {
                int m = et * 16 + (lane >> 4) * 4 + r;
                float h = acc[et][nt][r] + bb;
                *(__bf16*)(xw + m * 512 + (((unsigned)(n * 2)) ^ (((unsigned)(m & 7)) << 4)))
                    = (__bf16)(h * __builtin_amdgcn_rcpf(1.f + __expf(-h)));
            }
    }
    __syncthreads();

    // ================= Layer 2: K=256 (reads H, rewrites H) =================
#pragma unroll
    for (int et = 0; et < 4; ++et)
#pragma unroll
        for (int nt = 0; nt < 4; ++nt) acc[et][nt] = (f32x4)0.f;
    {
        const __bf16* bp[4];
#pragma unroll
        for (int nt = 0; nt < 4; ++nt)
            bp[nt] = &W2t[(size_t)(nbase + nt * 16 + l15) * TWOF + kg];
        bf16x8 bcur[4];
#pragma unroll
        for (int nt = 0; nt < 4; ++nt) bcur[nt] = *(const bf16x8*)bp[nt];
        __builtin_amdgcn_s_setprio(1);
#pragma unroll
        for (int kc = 0; kc < TWOF; kc += 32) {
            bf16x8 bnxt[4];
            if (kc + 32 < TWOF) {
#pragma unroll
                for (int nt = 0; nt < 4; ++nt)
                    bnxt[nt] = *(const bf16x8*)(bp[nt] + kc + 32);
            }
            bf16x8 a[4];
#pragma unroll
            for (int et = 0; et < 4; ++et)
                a[et] = *(const bf16x8*)(xb + et * 8192 + (((unsigned)((kc + kg) * 2)) ^ axor));
#pragma unroll
            for (int nt = 0; nt < 4; ++nt)
#pragma unroll
                for (int et = 0; et < 4; ++et)
                    acc[et][nt] = __builtin_amdgcn_mfma_f32_16x16x32_bf16(a[et], bcur[nt], acc[et][nt], 0, 0, 0);
#pragma unroll
            for (int nt = 0; nt < 4; ++nt) bcur[nt] = bnxt[nt];
        }
        __builtin_amdgcn_s_setprio(0);
    }
    __syncthreads();   // all h1 reads complete before overwrite
#pragma unroll
    for (int nt = 0; nt < 4; ++nt) {
        int n = nbase + nt * 16 + l15;
        float bb = b2[n];
#pragma unroll
        for (int et = 0; et < 4; ++et)
#pragma unroll
            for (int r = 0; r < 4; ++r) {
                int m = et * 16 + (lane >> 4) * 4 + r;
                float h = acc[et][nt][r] + bb;
                *(__bf16*)(xw + m * 512 + (((unsigned)(n * 2)) ^ (((unsigned)(m & 7)) << 4)))
                    = (__bf16)(h * __builtin_amdgcn_rcpf(1.f + __expf(-h)));
            }
    }
    __syncthreads();

    // ================= Layer 3: K=256 (reads H) =================
#pragma unroll
    for (int et = 0; et < 4; ++et)
#pragma unroll
        for (int nt = 0; nt < 4; ++nt) acc[et][nt] = (f32x4)0.f;
    {
        const __bf16* bp[4];
#pragma unroll
        for (int nt = 0; nt < 4; ++nt) {
            int rowbase = ((nt >= 2) ? FDIM : 0) + wave * 32 + (nt & 1) * 16 + l15;
            bp[nt] = &W3t[(size_t)rowbase * TWOF + kg];
        }
        bf16x8 bcur[4];
#pragma unroll
        for (int nt = 0; nt < 4; ++nt) bcur[nt] = *(const bf16x8*)bp[nt];
        __builtin_amdgcn_s_setprio(1);
#pragma unroll
        for (int kc = 0; kc < TWOF; kc += 32) {
            bf16x8 bnxt[4];
            if (kc + 32 < TWOF) {
#pragma unroll
                for (int nt = 0; nt < 4; ++nt)
                    bnxt[nt] = *(const bf16x8*)(bp[nt] + kc + 32);
            }
            bf16x8 a[4];
#pragma unroll
            for (int et = 0; et < 4; ++et)
                a[et] = *(const bf16x8*)(xb + et * 8192 + (((unsigned)((kc + kg) * 2)) ^ axor));
#pragma unroll
            for (int nt = 0; nt < 4; ++nt)
#pragma unroll
                for (int et = 0; et < 4; ++et)
                    acc[et][nt] = __builtin_amdgcn_mfma_f32_16x16x32_bf16(a[et], bcur[nt], acc[et][nt], 0, 0, 0);
#pragma unroll
            for (int nt = 0; nt < 4; ++nt) bcur[nt] = bnxt[nt];
        }
        __builtin_amdgcn_s_setprio(0);
    }

    float b3v[4];
#pragma unroll
    for (int nt = 0; nt < 4; ++nt) {
        int n = wave * 32 + (nt & 1) * 16 + l15;
        b3v[nt] = (nt < 2) ? bsm[n] : bvm[n];
    }

    if (CSR) {
        __syncthreads();   // all H reads complete before EO staging overwrites buffer
#pragma unroll
        for (int nt = 0; nt < 4; ++nt) {
            int col = ((nt >= 2) ? FDIM : 0) + wave * 32 + (nt & 1) * 16 + l15;
            float bb = b3v[nt];
#pragma unroll
            for (int et = 0; et < 4; ++et)
#pragma unroll
                for (int r = 0; r < 4; ++r) {
                    int m = et * 16 + (lane >> 4) * 4 + r;
                    *(__bf16*)(xw + m * 512 + (((unsigned)(col * 2)) ^ (((unsigned)(m & 7)) << 4)))
                        = (__bf16)(acc[et][nt][r] + bb);
                }
        }
        __syncthreads();
        u32x4v* dst4 = (u32x4v*)EO;
#pragma unroll
        for (int j = 0; j < 8; ++j) {
            int flat = j * 256 + t;          // 0..2047
            int row = flat >> 5, slot = flat & 31;
            if (!svalid[row]) continue;
            u32x4v val = *(const u32x4v*)((const char*)&Xs[0][0] + row * 512
                                          + ((slot ^ (row & 7)) << 4));
            __builtin_nontemporal_store(val, &dst4[(size_t)sperm[row] * 32 + slot]);
        }
    } else {
        float* outs = out;
        float* outv = out + (size_t)N * FDIM;
#pragma unroll
        for (int et = 0; et < 4; ++et) {
#pragma unroll
            for (int r = 0; r < 4; ++r) {
                int m = et * 16 + (lane >> 4) * 4 + r;
                if (!svalid[m]) continue;
                int dst = sdst[m];
                float dx = sdir[0][m], dy = sdir[1][m], dz = sdir[2][m];
#pragma unroll
                for (int nt = 0; nt < 4; ++nt) {
                    int n = wave * 32 + (nt & 1) * 16 + l15;
                    float val = acc[et][nt][r] + b3v[nt];
                    if (nt < 2) {
                        atomicAdd(&outs[dst * FDIM + n], val);
                    } else {
                        int base = dst * 3 * FDIM + n;
                        atomicAdd(&outv[base],            dx * val);
                        atomicAdd(&outv[base + FDIM],     dy * val);
                        atomicAdd(&outv[base + 2 * FDIM], dz * val);
                    }
                }
            }
        }
    }
}

// ---------------- node aggregation: fully streaming (EO/dir pre-sorted) ----------------

__launch_bounds__(256)
__global__ void node_kernel(const float* __restrict__ s, const float* __restrict__ v,
                            const __bf16* __restrict__ EO,
                            const float* __restrict__ dirx, const float* __restrict__ diry,
                            const float* __restrict__ dirz,
                            const int* __restrict__ rs,
                            float* __restrict__ out, int N) {
    int wave = threadIdx.x >> 6, lane = threadIdx.x & 63;
    int n = blockIdx.x * 4 + wave;
    if (n >= N) return;
    int beg = rs[n], end = rs[n + 1];

    float a0 = 0.f, a1 = 0.f;
    float vx0 = 0.f, vx1 = 0.f, vy0 = 0.f, vy1 = 0.f, vz0 = 0.f, vz1 = 0.f;
    const unsigned* EO32 = (const unsigned*)EO;

#pragma unroll 2
    for (int i = beg; i < end; ++i) {
        unsigned pds = __builtin_nontemporal_load(&EO32[(size_t)i * 128 + lane]);
        unsigned pvm = __builtin_nontemporal_load(&EO32[(size_t)i * 128 + 64 + lane]);
        float dx = __builtin_nontemporal_load(&dirx[i]);
        float dy = __builtin_nontemporal_load(&diry[i]);
        float dz = __builtin_nontemporal_load(&dirz[i]);
        float d0 = blo(pds), d1 = bhi(pds);
        float m0 = blo(pvm), m1 = bhi(pvm);
        a0 += d0; a1 += d1;
        vx0 = fmaf(dx, m0, vx0); vx1 = fmaf(dx, m1, vx1);
        vy0 = fmaf(dy, m0, vy0); vy1 = fmaf(dy, m1, vy1);
        vz0 = fmaf(dz, m0, vz0); vz1 = fmaf(dz, m1, vz1);
    }

    f32x2 sv = *((const f32x2*)&s[(size_t)n * FDIM] + lane);
    f32x2 o0 = { sv.x + a0, sv.y + a1 };
    __builtin_nontemporal_store(o0, (f32x2*)&out[(size_t)n * FDIM] + lane);

    const float* vb = &v[(size_t)n * 3 * FDIM];
    float* ovb = &out[(size_t)N * FDIM + (size_t)n * 3 * FDIM];
    f32x2 vv;
    vv = *((const f32x2*)vb + lane);
    f32x2 ox = { vv.x + vx0, vv.y + vx1 };
    __builtin_nontemporal_store(ox, (f32x2*)ovb + lane);
    vv = *((const f32x2*)(vb + FDIM) + lane);
    f32x2 oy = { vv.x + vy0, vv.y + vy1 };
    __builtin_nontemporal_store(oy, (f32x2*)(ovb + FDIM) + lane);
    vv = *((const f32x2*)(vb + 2 * FDIM) + lane);
    f32x2 oz = { vv.x + vz0, vv.y + vz1 };
    __builtin_nontemporal_store(oz, (f32x2*)(ovb + 2 * FDIM) + lane);
}

// ---------------- host ----------------

static inline size_t align256(size_t x) { return (x + 255) & ~(size_t)255; }

extern "C" void kernel_launch(void* const* d_in, const int* in_sizes, int n_in,
                              void* d_out, int out_size, void* d_ws, size_t ws_size,
                              hipStream_t stream) {
    const float* s   = (const float*)d_in[0];
    const float* v   = (const float*)d_in[1];
    const float* pos = (const float*)d_in[2];
    const int*   ei  = (const int*)d_in[3];
    const float* W1  = (const float*)d_in[4];
    const float* b1  = (const float*)d_in[5];
    const float* W2  = (const float*)d_in[6];
    const float* b2  = (const float*)d_in[7];
    const float* Wsm = (const float*)d_in[8];
    const float* bsm = (const float*)d_in[9];
    const float* Wvm = (const float*)d_in[10];
    const float* bvm = (const float*)d_in[11];
    const float* centers = (const float*)d_in[12];
    const float* widths  = (const float*)d_in[13];
    float* out = (float*)d_out;

    int N = in_sizes[0] / FDIM;
    int E = in_sizes[3] / 2;
    int nblocks = (E + TE - 1) / TE;

    // workspace layout
    size_t off = 0;
    int* flag = (int*)((char*)d_ws + off);           off = align256(off + 4);
    __bf16* W1t = (__bf16*)((char*)d_ws + off);      off = align256(off + (size_t)256 * K1PAD * 2);
    __bf16* W2t = (__bf16*)((char*)d_ws + off);      off = align256(off + (size_t)256 * TWOF * 2);
    __bf16* W3t = (__bf16*)((char*)d_ws + off);      off = align256(off + (size_t)256 * TWOF * 2);
    __bf16* s16 = (__bf16*)((char*)d_ws + off);      off = align256(off + (size_t)N * FDIM * 2);
    int* hist   = (int*)((char*)d_ws + off);         off = align256(off + (size_t)N * 4);
    int* loc    = (int*)((char*)d_ws + off);         off = align256(off + (size_t)N * 4);
    int* bsum   = (int*)((char*)d_ws + off);         off = align256(off + 1024);
    int* rs     = (int*)((char*)d_ws + off);         off = align256(off + (size_t)(N + 1) * 4);
    int* cursor = (int*)((char*)d_ws + off);         off = align256(off + (size_t)N * 4);
    int* perm   = (int*)((char*)d_ws + off);         off = align256(off + (size_t)E * 4);
    float* dirx = (float*)((char*)d_ws + off);       off = align256(off + (size_t)E * 4);
    float* diry = (float*)((char*)d_ws + off);       off = align256(off + (size_t)E * 4);
    float* dirz = (float*)((char*)d_ws + off);       off = align256(off + (size_t)E * 4);
    __bf16* EO  = (__bf16*)((char*)d_ws + off);      off = align256(off + (size_t)E * 256 * 2);
    bool use_csr = (off <= ws_size);

    int nsample = E < 1024 ? E : 1024;
    hipLaunchKernelGGL(sniff_idx, dim3(1), dim3(256), 0, stream, ei, nsample, flag);

    int nprep = 256 * K1PAD + 2 * 256 * TWOF;
    hipLaunchKernelGGL(prep_weights, dim3((nprep + 255) / 256), dim3(256), 0, stream,
                       W1, W2, Wsm, Wvm, W1t, W2t, W3t);

    int n8 = (N * FDIM) / 8;
    hipLaunchKernelGGL(prep_s, dim3((n8 + 255) / 256), dim3(256), 0, stream,
                       (const float4*)s, (bf16x8*)s16, n8);

    if (use_csr) {
        int nb = (N + 1023) / 1024;
        hipLaunchKernelGGL(zero_hist, dim3((N + 255) / 256), dim3(256), 0, stream, hist, N);
        hipLaunchKernelGGL(hist_k, dim3((E + 255) / 256), dim3(256), 0, stream, ei, flag, hist, E);
        hipLaunchKernelGGL(scan_a, dim3(nb), dim3(256), 0, stream, hist, loc, bsum, N);
        hipLaunchKernelGGL(scan_b, dim3(1), dim3(64), 0, stream, bsum, nb);
        hipLaunchKernelGGL(scan_c, dim3((N + 255) / 256), dim3(256), 0, stream, loc, bsum, rs, cursor, N, E);
        hipLaunchKernelGGL(scatter_k, dim3((E + 255) / 256), dim3(256), 0, stream, ei, flag, cursor, perm, E);

        hipLaunchKernelGGL(edge_kernel<1>, dim3(nblocks), dim3(256), 0, stream,
                           s16, pos, ei, b1, b2, bsm, bvm, centers, widths,
                           W1t, W2t, W3t, flag, perm, EO, dirx, diry, dirz, out, N, E);

        hipLaunchKernelGGL(node_kernel, dim3((N + 3) / 4), dim3(256), 0, stream,
                           s, v, EO, dirx, diry, dirz, rs, out, N);
    } else {
        int nf4    = (N * FDIM) / 4;
        int total4 = N * FDIM;
        hipLaunchKernelGGL(init_out, dim3(8192), dim3(256), 0, stream,
                           (const float4*)s, (const float4*)v, (float4*)out, nf4, total4);
        hipLaunchKernelGGL(edge_kernel<0>, dim3(nblocks), dim3(256), 0, stream,
                           s16, pos, ei, b1, b2, bsm, bvm, centers, widths,
                           W1t, W2t, W3t, flag, perm, EO, dirx, diry, dirz, out, N, E);
    }
}

// Round 6
// 696.856 us; speedup vs baseline: 1.1864x; 1.1864x over previous
//
#include <hip/hip_runtime.h>
#include <math.h>

#define FDIM   128
#define TWOF   256
#define NRBF_  20
#define INDIM  276
#define K1PAD  288          // INDIM padded to multiple of 32
#define XS     296          // shared-buffer row stride in bf16 (odd # of 16B chunks)
#define TE     64           // edges per workgroup (proven best: 4 blocks/CU)

typedef __bf16 bf16x8 __attribute__((ext_vector_type(8)));
typedef float  f32x4  __attribute__((ext_vector_type(4)));
typedef float  f32x2  __attribute__((ext_vector_type(2)));
typedef unsigned int u32x4v __attribute__((ext_vector_type(4)));

__device__ inline float blo(unsigned p){ return __uint_as_float(p << 16); }
__device__ inline float bhi(unsigned p){ return __uint_as_float(p & 0xffff0000u); }

// ---------------- helper kernels ----------------

__global__ void sniff_idx(const int* __restrict__ ei, int nsample, int* __restrict__ flag) {
    __shared__ int any;
    if (threadIdx.x == 0) any = 0;
    __syncthreads();
    int nz = 0;
    for (int i = threadIdx.x; i < nsample; i += blockDim.x)
        nz |= (ei[2 * i + 1] != 0);
    if (nz) atomicOr(&any, 1);
    __syncthreads();
    if (threadIdx.x == 0) *flag = any;
}

__global__ void init_out(const float4* __restrict__ s4, const float4* __restrict__ v4,
                         float4* __restrict__ out4, int nf4, int total4) {
    for (int i = blockIdx.x * blockDim.x + threadIdx.x; i < total4;
         i += gridDim.x * blockDim.x)
        out4[i] = (i < nf4) ? s4[i] : v4[i - nf4];
}

// fused one-shot prep: weight transpose+cast, s->bf16 convert, hist zero
__global__ void prep_all(const float* __restrict__ W1, const float* __restrict__ W2,
                         const float* __restrict__ Ws, const float* __restrict__ Wv,
                         __bf16* __restrict__ W1t, __bf16* __restrict__ W2t,
                         __bf16* __restrict__ W3t,
                         const float4* __restrict__ s4, bf16x8* __restrict__ s16o, int n8,
                         int* __restrict__ hist, int N) {
    int id = blockIdx.x * 256 + threadIdx.x;
    const int n1 = 256 * K1PAD;
    const int nW = n1 + 131072;
    if (id < n1) {
        int n = id / K1PAD, k = id - n * K1PAD;
        W1t[id] = (k < INDIM) ? (__bf16)W1[k * TWOF + n] : (__bf16)0.f;
    } else if (id < n1 + 65536) {
        int j = id - n1; int n = j >> 8, k = j & 255;
        W2t[j] = (__bf16)W2[k * TWOF + n];
    } else if (id < nW) {
        int j = id - n1 - 65536; int n = j >> 8, k = j & 255;
        W3t[j] = (n < FDIM) ? (__bf16)Ws[k * FDIM + n]
                            : (__bf16)Wv[k * FDIM + (n - FDIM)];
    } else if (id < nW + n8) {
        int i = id - nW;
        float4 a = s4[i * 2], b = s4[i * 2 + 1];
        bf16x8 o;
        o[0] = (__bf16)a.x; o[1] = (__bf16)a.y; o[2] = (__bf16)a.z; o[3] = (__bf16)a.w;
        o[4] = (__bf16)b.x; o[5] = (__bf16)b.y; o[6] = (__bf16)b.z; o[7] = (__bf16)b.w;
        s16o[i] = o;
    } else if (id < nW + n8 + N) {
        hist[id - nW - n8] = 0;
    }
}

// ---------------- CSR build ----------------

__global__ void hist_k(const int* __restrict__ ei, const int* __restrict__ flag,
                       int* __restrict__ hist, int E) {
    int e = blockIdx.x * 256 + threadIdx.x;
    if (e >= E) return;
    int dst = (*flag == 0) ? ei[2 * (E + e)] : ei[E + e];
    atomicAdd(&hist[dst], 1);
}

__global__ void scan_a(const int* __restrict__ hist, int* __restrict__ loc,
                       int* __restrict__ bsum, int N) {
    __shared__ int sums[256];
    int t = threadIdx.x;
    int base = blockIdx.x * 1024 + t * 4;
    int v0 = (base + 0 < N) ? hist[base + 0] : 0;
    int v1 = (base + 1 < N) ? hist[base + 1] : 0;
    int v2 = (base + 2 < N) ? hist[base + 2] : 0;
    int v3 = (base + 3 < N) ? hist[base + 3] : 0;
    int s = v0 + v1 + v2 + v3;
    sums[t] = s;
    __syncthreads();
    for (int off = 1; off < 256; off <<= 1) {
        int x = (t >= off) ? sums[t - off] : 0;
        __syncthreads();
        sums[t] += x;
        __syncthreads();
    }
    int excl = sums[t] - s;
    if (t == 255) bsum[blockIdx.x] = sums[255];
    if (base + 0 < N) loc[base + 0] = excl; excl += v0;
    if (base + 1 < N) loc[base + 1] = excl; excl += v1;
    if (base + 2 < N) loc[base + 2] = excl; excl += v2;
    if (base + 3 < N) loc[base + 3] = excl;
}

__global__ void scan_b(int* __restrict__ bsum, int nb) {
    if (threadIdx.x == 0 && blockIdx.x == 0) {
        int run = 0;
        for (int i = 0; i < nb; ++i) { int v = bsum[i]; bsum[i] = run; run += v; }
    }
}

__global__ void scan_c(const int* __restrict__ loc, const int* __restrict__ bsum,
                       int* __restrict__ rs, int* __restrict__ cursor, int N, int E) {
    int i = blockIdx.x * 256 + threadIdx.x;
    if (i < N) {
        int v = loc[i] + bsum[i >> 10];
        rs[i] = v; cursor[i] = v;
    }
    if (i == 0) rs[N] = E;
}

// store edge -> CSR slot (perm), not slot -> edge
__global__ void scatter_k(const int* __restrict__ ei, const int* __restrict__ flag,
                          int* __restrict__ cursor, int* __restrict__ perm, int E) {
    int e = blockIdx.x * 256 + threadIdx.x;
    if (e >= E) return;
    int dst = (*flag == 0) ? ei[2 * (E + e)] : ei[E + e];
    int pos = atomicAdd(&cursor[dst], 1);
    perm[e] = pos;
}

// ---------------- main edge kernel ----------------
// Single LDS buffer Sb holds X (L1 input), then H (L1/L2 output), then EO staging.
// TE=64 / 256 threads / 4 waves, 4 blocks/CU (39.9KB LDS): proven best config.
// Phase A (per-edge prep, cols 256..287) and Phase B (s-gather, cols 0..255)
// run CONCURRENTLY in one barrier region: B re-reads ei directly (L1-hot)
// instead of waiting for A's LDS arrays.

template<int CSR>
__launch_bounds__(256, 4)
__global__ void edge_kernel(const __bf16* __restrict__ s16,
                            const float* __restrict__ pos,
                            const int* __restrict__ ei,
                            const float* __restrict__ b1, const float* __restrict__ b2,
                            const float* __restrict__ bsm, const float* __restrict__ bvm,
                            const float* __restrict__ centers, const float* __restrict__ widths,
                            const __bf16* __restrict__ W1t, const __bf16* __restrict__ W2t,
                            const __bf16* __restrict__ W3t,
                            const int* __restrict__ flag,
                            const int* __restrict__ perm,
                            __bf16* __restrict__ EO,
                            float* __restrict__ dirx, float* __restrict__ diry,
                            float* __restrict__ dirz,
                            float* __restrict__ out, int N, int E) {
    __shared__ __align__(16) __bf16 Sb[TE][XS];
    __shared__ float sdir[3][TE];
    __shared__ int ssrc[TE], sdst[TE], svalid[TE], sperm[TE];

    const int t    = threadIdx.x;
    const int lane = t & 63;
    const int wave = t >> 6;
    const int e0   = blockIdx.x * TE;
    const int i64  = (*flag == 0);

    // ---- Phase B: gather s16[src]/s16[dst] -> X cols 0..255 (bf16, 16B/lane)
    // Reads ei directly so it does NOT depend on Phase A. Issued first so the
    // random 16B gathers are in flight while Phase A's pos-chain runs.
    {
        const int pair = lane >> 5;        // which of 2 edges this iter
        const int half = (lane >> 4) & 1;  // 0: src, 1: dst
        const int q    = lane & 15;        // 16-byte chunk
        const bf16x8* s8 = (const bf16x8*)s16;
#pragma unroll
        for (int i = 0; i < 8; ++i) {
            int eL = wave * 16 + i * 2 + pair;
            int e = e0 + eL;
            int ec = (e < E) ? e : 0;
            int idx = half ? (E + ec) : ec;
            int node = i64 ? ei[2 * idx] : ei[idx];
            bf16x8 x = s8[node * 16 + q];
            *(bf16x8*)&Sb[eL][half * FDIM + q * 8] = x;
        }
    }

    // ---- Phase A: per-edge prep, 4 threads per edge (cols 256..287 + side arrays)
    {
        const int eL  = t >> 2;      // 0..63 local edge
        const int sub = t & 3;       // 0..3 RBF slice
        int e = e0 + eL;
        int valid = (e < E);
        int srcn = 0, dstn = 0;
        if (valid) {
            if (i64) { srcn = ei[2 * e]; dstn = ei[2 * (E + e)]; }
            else     { srcn = ei[e];     dstn = ei[E + e]; }
        }
        float rx = pos[dstn * 3 + 0] - pos[srcn * 3 + 0];
        float ry = pos[dstn * 3 + 1] - pos[srcn * 3 + 1];
        float rz = pos[dstn * 3 + 2] - pos[srcn * 3 + 2];
        float dist = sqrtf(rx * rx + ry * ry + rz * rz);
        if (sub == 0) {
            ssrc[eL] = srcn; sdst[eL] = dstn; svalid[eL] = valid;
            float inv = dist > 0.f ? 1.f / dist : 0.f;
            float dx = rx * inv, dy = ry * inv, dz = rz * inv;
            sdir[0][eL] = dx; sdir[1][eL] = dy; sdir[2][eL] = dz;
            int p = 0;
            if (CSR && valid) {
                p = perm[e];
                __builtin_nontemporal_store(dx, &dirx[p]);
                __builtin_nontemporal_store(dy, &diry[p]);
                __builtin_nontemporal_store(dz, &dirz[p]);
            }
            sperm[eL] = p;
        }
#pragma unroll
        for (int k8 = 0; k8 < 8; ++k8) {
            int k = sub * 8 + k8;
            float val = 0.f;
            if (k < NRBF_) {
                float u = (dist - centers[k]) / (widths[k] + 1e-8f);
                val = __expf(-u * u);
            }
            Sb[eL][TWOF + k] = (__bf16)val;
        }
    }
    __syncthreads();

    const int l15 = lane & 15;
    const int kg  = (lane >> 4) * 8;
    const int nbase = wave * 64;

    f32x4 acc[4][4];

    // ================= Layer 1: K=288 (reads X) =================
#pragma unroll
    for (int et = 0; et < 4; ++et)
#pragma unroll
        for (int nt = 0; nt < 4; ++nt) acc[et][nt] = (f32x4)0.f;
    {
        const __bf16* bp[4];
#pragma unroll
        for (int nt = 0; nt < 4; ++nt)
            bp[nt] = &W1t[(size_t)(nbase + nt * 16 + l15) * K1PAD + kg];
        bf16x8 bcur[4];
#pragma unroll
        for (int nt = 0; nt < 4; ++nt) bcur[nt] = *(const bf16x8*)bp[nt];
        __builtin_amdgcn_s_setprio(1);
#pragma unroll
        for (int kc = 0; kc < K1PAD; kc += 32) {
            bf16x8 bnxt[4];
            if (kc + 32 < K1PAD) {
#pragma unroll
                for (int nt = 0; nt < 4; ++nt)
                    bnxt[nt] = *(const bf16x8*)(bp[nt] + kc + 32);
            }
            bf16x8 a[4];
#pragma unroll
            for (int et = 0; et < 4; ++et)
                a[et] = *(const bf16x8*)&Sb[et * 16 + l15][kc + kg];
#pragma unroll
            for (int nt = 0; nt < 4; ++nt)
#pragma unroll
                for (int et = 0; et < 4; ++et)
                    acc[et][nt] = __builtin_amdgcn_mfma_f32_16x16x32_bf16(a[et], bcur[nt], acc[et][nt], 0, 0, 0);
#pragma unroll
            for (int nt = 0; nt < 4; ++nt) bcur[nt] = bnxt[nt];
        }
        __builtin_amdgcn_s_setprio(0);
    }
    __syncthreads();   // all X reads complete before H overwrites the buffer
#pragma unroll
    for (int nt = 0; nt < 4; ++nt) {
        int n = nbase + nt * 16 + l15;
        float bb = b1[n];
#pragma unroll
        for (int et = 0; et < 4; ++et)
#pragma unroll
            for (int r = 0; r < 4; ++r) {
                int m = et * 16 + (lane >> 4) * 4 + r;
                float h = acc[et][nt][r] + bb;
                Sb[m][n] = (__bf16)(h * __builtin_amdgcn_rcpf(1.f + __expf(-h)));
            }
    }
    __syncthreads();

    // ================= Layer 2: K=256 (reads H, rewrites H) =================
#pragma unroll
    for (int et = 0; et < 4; ++et)
#pragma unroll
        for (int nt = 0; nt < 4; ++nt) acc[et][nt] = (f32x4)0.f;
    {
        const __bf16* bp[4];
#pragma unroll
        for (int nt = 0; nt < 4; ++nt)
            bp[nt] = &W2t[(size_t)(nbase + nt * 16 + l15) * TWOF + kg];
        bf16x8 bcur[4];
#pragma unroll
        for (int nt = 0; nt < 4; ++nt) bcur[nt] = *(const bf16x8*)bp[nt];
        __builtin_amdgcn_s_setprio(1);
#pragma unroll
        for (int kc = 0; kc < TWOF; kc += 32) {
            bf16x8 bnxt[4];
            if (kc + 32 < TWOF) {
#pragma unroll
                for (int nt = 0; nt < 4; ++nt)
                    bnxt[nt] = *(const bf16x8*)(bp[nt] + kc + 32);
            }
            bf16x8 a[4];
#pragma unroll
            for (int et = 0; et < 4; ++et)
                a[et] = *(const bf16x8*)&Sb[et * 16 + l15][kc + kg];
#pragma unroll
            for (int nt = 0; nt < 4; ++nt)
#pragma unroll
                for (int et = 0; et < 4; ++et)
                    acc[et][nt] = __builtin_amdgcn_mfma_f32_16x16x32_bf16(a[et], bcur[nt], acc[et][nt], 0, 0, 0);
#pragma unroll
            for (int nt = 0; nt < 4; ++nt) bcur[nt] = bnxt[nt];
        }
        __builtin_amdgcn_s_setprio(0);
    }
    __syncthreads();   // all h1 reads complete before overwrite
#pragma unroll
    for (int nt = 0; nt < 4; ++nt) {
        int n = nbase + nt * 16 + l15;
        float bb = b2[n];
#pragma unroll
        for (int et = 0; et < 4; ++et)
#pragma unroll
            for (int r = 0; r < 4; ++r) {
                int m = et * 16 + (lane >> 4) * 4 + r;
                float h = acc[et][nt][r] + bb;
                Sb[m][n] = (__bf16)(h * __builtin_amdgcn_rcpf(1.f + __expf(-h)));
            }
    }
    __syncthreads();

    // ================= Layer 3: K=256 (reads H) =================
#pragma unroll
    for (int et = 0; et < 4; ++et)
#pragma unroll
        for (int nt = 0; nt < 4; ++nt) acc[et][nt] = (f32x4)0.f;
    {
        const __bf16* bp[4];
#pragma unroll
        for (int nt = 0; nt < 4; ++nt) {
            int rowbase = ((nt >= 2) ? FDIM : 0) + wave * 32 + (nt & 1) * 16 + l15;
            bp[nt] = &W3t[(size_t)rowbase * TWOF + kg];
        }
        bf16x8 bcur[4];
#pragma unroll
        for (int nt = 0; nt < 4; ++nt) bcur[nt] = *(const bf16x8*)bp[nt];
        __builtin_amdgcn_s_setprio(1);
#pragma unroll
        for (int kc = 0; kc < TWOF; kc += 32) {
            bf16x8 bnxt[4];
            if (kc + 32 < TWOF) {
#pragma unroll
                for (int nt = 0; nt < 4; ++nt)
                    bnxt[nt] = *(const bf16x8*)(bp[nt] + kc + 32);
            }
            bf16x8 a[4];
#pragma unroll
            for (int et = 0; et < 4; ++et)
                a[et] = *(const bf16x8*)&Sb[et * 16 + l15][kc + kg];
#pragma unroll
            for (int nt = 0; nt < 4; ++nt)
#pragma unroll
                for (int et = 0; et < 4; ++et)
                    acc[et][nt] = __builtin_amdgcn_mfma_f32_16x16x32_bf16(a[et], bcur[nt], acc[et][nt], 0, 0, 0);
#pragma unroll
            for (int nt = 0; nt < 4; ++nt) bcur[nt] = bnxt[nt];
        }
        __builtin_amdgcn_s_setprio(0);
    }

    float b3v[4];
#pragma unroll
    for (int nt = 0; nt < 4; ++nt) {
        int n = wave * 32 + (nt & 1) * 16 + l15;
        b3v[nt] = (nt < 2) ? bsm[n] : bvm[n];
    }

    if (CSR) {
        __syncthreads();   // all H reads complete before EO staging overwrites buffer
        __bf16 (*EOs)[XS] = (__bf16(*)[XS])(&Sb[0][0]);
#pragma unroll
        for (int nt = 0; nt < 4; ++nt) {
            int col = ((nt >= 2) ? FDIM : 0) + wave * 32 + (nt & 1) * 16 + l15;
            float bb = b3v[nt];
#pragma unroll
            for (int et = 0; et < 4; ++et)
#pragma unroll
                for (int r = 0; r < 4; ++r) {
                    int m = et * 16 + (lane >> 4) * 4 + r;
                    EOs[m][col] = (__bf16)(acc[et][nt][r] + bb);
                }
        }
        __syncthreads();
        u32x4v* dst4 = (u32x4v*)EO;
#pragma unroll
        for (int j = 0; j < 8; ++j) {
            int flat = j * 256 + t;          // 0..2047
            int row = flat >> 5, col = flat & 31;
            if (!svalid[row]) continue;
            __builtin_nontemporal_store(*(const u32x4v*)&EOs[row][col * 8],
                                        &dst4[(size_t)sperm[row] * 32 + col]);
        }
    } else {
        float* outs = out;
        float* outv = out + (size_t)N * FDIM;
#pragma unroll
        for (int et = 0; et < 4; ++et) {
#pragma unroll
            for (int r = 0; r < 4; ++r) {
                int m = et * 16 + (lane >> 4) * 4 + r;
                if (!svalid[m]) continue;
                int dst = sdst[m];
                float dx = sdir[0][m], dy = sdir[1][m], dz = sdir[2][m];
#pragma unroll
                for (int nt = 0; nt < 4; ++nt) {
                    int n = wave * 32 + (nt & 1) * 16 + l15;
                    float val = acc[et][nt][r] + b3v[nt];
                    if (nt < 2) {
                        atomicAdd(&outs[dst * FDIM + n], val);
                    } else {
                        int base = dst * 3 * FDIM + n;
                        atomicAdd(&outv[base],            dx * val);
                        atomicAdd(&outv[base + FDIM],     dy * val);
                        atomicAdd(&outv[base + 2 * FDIM], dz * val);
                    }
                }
            }
        }
    }
}

// ---------------- node aggregation: fully streaming (EO/dir pre-sorted) ----------------

__launch_bounds__(256)
__global__ void node_kernel(const float* __restrict__ s, const float* __restrict__ v,
                            const __bf16* __restrict__ EO,
                            const float* __restrict__ dirx, const float* __restrict__ diry,
                            const float* __restrict__ dirz,
                            const int* __restrict__ rs,
                            float* __restrict__ out, int N) {
    int wave = threadIdx.x >> 6, lane = threadIdx.x & 63;
    int n = blockIdx.x * 4 + wave;
    if (n >= N) return;
    int beg = rs[n], end = rs[n + 1];

    float a0 = 0.f, a1 = 0.f;
    float vx0 = 0.f, vx1 = 0.f, vy0 = 0.f, vy1 = 0.f, vz0 = 0.f, vz1 = 0.f;
    const unsigned* EO32 = (const unsigned*)EO;

#pragma unroll 2
    for (int i = beg; i < end; ++i) {
        unsigned pds = __builtin_nontemporal_load(&EO32[(size_t)i * 128 + lane]);
        unsigned pvm = __builtin_nontemporal_load(&EO32[(size_t)i * 128 + 64 + lane]);
        float dx = __builtin_nontemporal_load(&dirx[i]);
        float dy = __builtin_nontemporal_load(&diry[i]);
        float dz = __builtin_nontemporal_load(&dirz[i]);
        float d0 = blo(pds), d1 = bhi(pds);
        float m0 = blo(pvm), m1 = bhi(pvm);
        a0 += d0; a1 += d1;
        vx0 = fmaf(dx, m0, vx0); vx1 = fmaf(dx, m1, vx1);
        vy0 = fmaf(dy, m0, vy0); vy1 = fmaf(dy, m1, vy1);
        vz0 = fmaf(dz, m0, vz0); vz1 = fmaf(dz, m1, vz1);
    }

    f32x2 sv = *((const f32x2*)&s[(size_t)n * FDIM] + lane);
    f32x2 o0 = { sv.x + a0, sv.y + a1 };
    __builtin_nontemporal_store(o0, (f32x2*)&out[(size_t)n * FDIM] + lane);

    const float* vb = &v[(size_t)n * 3 * FDIM];
    float* ovb = &out[(size_t)N * FDIM + (size_t)n * 3 * FDIM];
    f32x2 vv;
    vv = *((const f32x2*)vb + lane);
    f32x2 ox = { vv.x + vx0, vv.y + vx1 };
    __builtin_nontemporal_store(ox, (f32x2*)ovb + lane);
    vv = *((const f32x2*)(vb + FDIM) + lane);
    f32x2 oy = { vv.x + vy0, vv.y + vy1 };
    __builtin_nontemporal_store(oy, (f32x2*)(ovb + FDIM) + lane);
    vv = *((const f32x2*)(vb + 2 * FDIM) + lane);
    f32x2 oz = { vv.x + vz0, vv.y + vz1 };
    __builtin_nontemporal_store(oz, (f32x2*)(ovb + 2 * FDIM) + lane);
}

// ---------------- host ----------------

static inline size_t align256(size_t x) { return (x + 255) & ~(size_t)255; }

extern "C" void kernel_launch(void* const* d_in, const int* in_sizes, int n_in,
                              void* d_out, int out_size, void* d_ws, size_t ws_size,
                              hipStream_t stream) {
    const float* s   = (const float*)d_in[0];
    const float* v   = (const float*)d_in[1];
    const float* pos = (const float*)d_in[2];
    const int*   ei  = (const int*)d_in[3];
    const float* W1  = (const float*)d_in[4];
    const float* b1  = (const float*)d_in[5];
    const float* W2  = (const float*)d_in[6];
    const float* b2  = (const float*)d_in[7];
    const float* Wsm = (const float*)d_in[8];
    const float* bsm = (const float*)d_in[9];
    const float* Wvm = (const float*)d_in[10];
    const float* bvm = (const float*)d_in[11];
    const float* centers = (const float*)d_in[12];
    const float* widths  = (const float*)d_in[13];
    float* out = (float*)d_out;

    int N = in_sizes[0] / FDIM;
    int E = in_sizes[3] / 2;
    int nblocks = (E + TE - 1) / TE;

    // workspace layout
    size_t off = 0;
    int* flag = (int*)((char*)d_ws + off);           off = align256(off + 4);
    __bf16* W1t = (__bf16*)((char*)d_ws + off);      off = align256(off + (size_t)256 * K1PAD * 2);
    __bf16* W2t = (__bf16*)((char*)d_ws + off);      off = align256(off + (size_t)256 * TWOF * 2);
    __bf16* W3t = (__bf16*)((char*)d_ws + off);      off = align256(off + (size_t)256 * TWOF * 2);
    __bf16* s16 = (__bf16*)((char*)d_ws + off);      off = align256(off + (size_t)N * FDIM * 2);
    int* hist   = (int*)((char*)d_ws + off);         off = align256(off + (size_t)N * 4);
    int* loc    = (int*)((char*)d_ws + off);         off = align256(off + (size_t)N * 4);
    int* bsum   = (int*)((char*)d_ws + off);         off = align256(off + 1024);
    int* rs     = (int*)((char*)d_ws + off);         off = align256(off + (size_t)(N + 1) * 4);
    int* cursor = (int*)((char*)d_ws + off);         off = align256(off + (size_t)N * 4);
    int* perm   = (int*)((char*)d_ws + off);         off = align256(off + (size_t)E * 4);
    float* dirx = (float*)((char*)d_ws + off);       off = align256(off + (size_t)E * 4);
    float* diry = (float*)((char*)d_ws + off);       off = align256(off + (size_t)E * 4);
    float* dirz = (float*)((char*)d_ws + off);       off = align256(off + (size_t)E * 4);
    __bf16* EO  = (__bf16*)((char*)d_ws + off);      off = align256(off + (size_t)E * 256 * 2);
    bool use_csr = (off <= ws_size);

    int nsample = E < 1024 ? E : 1024;
    hipLaunchKernelGGL(sniff_idx, dim3(1), dim3(256), 0, stream, ei, nsample, flag);

    int n8 = (N * FDIM) / 8;
    int nprep = 256 * K1PAD + 131072 + n8 + N;
    hipLaunchKernelGGL(prep_all, dim3((nprep + 255) / 256), dim3(256), 0, stream,
                       W1, W2, Wsm, Wvm, W1t, W2t, W3t,
                       (const float4*)s, (bf16x8*)s16, n8, hist, N);

    if (use_csr) {
        int nb = (N + 1023) / 1024;
        hipLaunchKernelGGL(hist_k, dim3((E + 255) / 256), dim3(256), 0, stream, ei, flag, hist, E);
        hipLaunchKernelGGL(scan_a, dim3(nb), dim3(256), 0, stream, hist, loc, bsum, N);
        hipLaunchKernelGGL(scan_b, dim3(1), dim3(64), 0, stream, bsum, nb);
        hipLaunchKernelGGL(scan_c, dim3((N + 255) / 256), dim3(256), 0, stream, loc, bsum, rs, cursor, N, E);
        hipLaunchKernelGGL(scatter_k, dim3((E + 255) / 256), dim3(256), 0, stream, ei, flag, cursor, perm, E);

        hipLaunchKernelGGL(edge_kernel<1>, dim3(nblocks), dim3(256), 0, stream,
                           s16, pos, ei, b1, b2, bsm, bvm, centers, widths,
                           W1t, W2t, W3t, flag, perm, EO, dirx, diry, dirz, out, N, E);

        hipLaunchKernelGGL(node_kernel, dim3((N + 3) / 4), dim3(256), 0, stream,
                           s, v, EO, dirx, diry, dirz, rs, out, N);
    } else {
        int nf4    = (N * FDIM) / 4;
        int total4 = N * FDIM;
        hipLaunchKernelGGL(init_out, dim3(8192), dim3(256), 0, stream,
                           (const float4*)s, (const float4*)v, (float4*)out, nf4, total4);
        hipLaunchKernelGGL(edge_kernel<0>, dim3(nblocks), dim3(256), 0, stream,
                           s16, pos, ei, b1, b2, bsm, bvm, centers, widths,
                           W1t, W2t, W3t, flag, perm, EO, dirx, diry, dirz, out, N, E);
    }
}

// Round 7
// 694.087 us; speedup vs baseline: 1.1911x; 1.0040x over previous
//
#include <hip/hip_runtime.h>
#include <math.h>

#define FDIM   128
#define TWOF   256
#define NRBF_  20
#define INDIM  276
#define K1PAD  288          // INDIM padded to multiple of 32
#define XS     296          // shared-buffer row stride in bf16 (odd # of 16B chunks)
#define TE     64           // edges per workgroup (proven best: 4 blocks/CU)

typedef __bf16 bf16x8 __attribute__((ext_vector_type(8)));
typedef __bf16 bf16x4 __attribute__((ext_vector_type(4)));
typedef float  f32x4  __attribute__((ext_vector_type(4)));
typedef float  f32x2  __attribute__((ext_vector_type(2)));
typedef unsigned int u32x4v __attribute__((ext_vector_type(4)));

__device__ inline float blo(unsigned p){ return __uint_as_float(p << 16); }
__device__ inline float bhi(unsigned p){ return __uint_as_float(p & 0xffff0000u); }

__device__ __forceinline__ float silu_f(float h) {
    return h * __builtin_amdgcn_rcpf(1.f + __expf(-h));
}

// ---------------- helper kernels ----------------

__global__ void sniff_idx(const int* __restrict__ ei, int nsample, int* __restrict__ flag) {
    __shared__ int any;
    if (threadIdx.x == 0) any = 0;
    __syncthreads();
    int nz = 0;
    for (int i = threadIdx.x; i < nsample; i += blockDim.x)
        nz |= (ei[2 * i + 1] != 0);
    if (nz) atomicOr(&any, 1);
    __syncthreads();
    if (threadIdx.x == 0) *flag = any;
}

__global__ void init_out(const float4* __restrict__ s4, const float4* __restrict__ v4,
                         float4* __restrict__ out4, int nf4, int total4) {
    for (int i = blockIdx.x * blockDim.x + threadIdx.x; i < total4;
         i += gridDim.x * blockDim.x)
        out4[i] = (i < nf4) ? s4[i] : v4[i - nf4];
}

// fused one-shot prep: weight transpose+cast, s->bf16 convert, hist zero
__global__ void prep_all(const float* __restrict__ W1, const float* __restrict__ W2,
                         const float* __restrict__ Ws, const float* __restrict__ Wv,
                         __bf16* __restrict__ W1t, __bf16* __restrict__ W2t,
                         __bf16* __restrict__ W3t,
                         const float4* __restrict__ s4, bf16x8* __restrict__ s16o, int n8,
                         int* __restrict__ hist, int N) {
    int id = blockIdx.x * 256 + threadIdx.x;
    const int n1 = 256 * K1PAD;
    const int nW = n1 + 131072;
    if (id < n1) {
        int n = id / K1PAD, k = id - n * K1PAD;
        W1t[id] = (k < INDIM) ? (__bf16)W1[k * TWOF + n] : (__bf16)0.f;
    } else if (id < n1 + 65536) {
        int j = id - n1; int n = j >> 8, k = j & 255;
        W2t[j] = (__bf16)W2[k * TWOF + n];
    } else if (id < nW) {
        int j = id - n1 - 65536; int n = j >> 8, k = j & 255;
        W3t[j] = (n < FDIM) ? (__bf16)Ws[k * FDIM + n]
                            : (__bf16)Wv[k * FDIM + (n - FDIM)];
    } else if (id < nW + n8) {
        int i = id - nW;
        float4 a = s4[i * 2], b = s4[i * 2 + 1];
        bf16x8 o;
        o[0] = (__bf16)a.x; o[1] = (__bf16)a.y; o[2] = (__bf16)a.z; o[3] = (__bf16)a.w;
        o[4] = (__bf16)b.x; o[5] = (__bf16)b.y; o[6] = (__bf16)b.z; o[7] = (__bf16)b.w;
        s16o[i] = o;
    } else if (id < nW + n8 + N) {
        hist[id - nW - n8] = 0;
    }
}

// ---------------- CSR build ----------------

__global__ void hist_k(const int* __restrict__ ei, const int* __restrict__ flag,
                       int* __restrict__ hist, int E) {
    int e = blockIdx.x * 256 + threadIdx.x;
    if (e >= E) return;
    int dst = (*flag == 0) ? ei[2 * (E + e)] : ei[E + e];
    atomicAdd(&hist[dst], 1);
}

__global__ void scan_a(const int* __restrict__ hist, int* __restrict__ loc,
                       int* __restrict__ bsum, int N) {
    __shared__ int sums[256];
    int t = threadIdx.x;
    int base = blockIdx.x * 1024 + t * 4;
    int v0 = (base + 0 < N) ? hist[base + 0] : 0;
    int v1 = (base + 1 < N) ? hist[base + 1] : 0;
    int v2 = (base + 2 < N) ? hist[base + 2] : 0;
    int v3 = (base + 3 < N) ? hist[base + 3] : 0;
    int s = v0 + v1 + v2 + v3;
    sums[t] = s;
    __syncthreads();
    for (int off = 1; off < 256; off <<= 1) {
        int x = (t >= off) ? sums[t - off] : 0;
        __syncthreads();
        sums[t] += x;
        __syncthreads();
    }
    int excl = sums[t] - s;
    if (t == 255) bsum[blockIdx.x] = sums[255];
    if (base + 0 < N) loc[base + 0] = excl; excl += v0;
    if (base + 1 < N) loc[base + 1] = excl; excl += v1;
    if (base + 2 < N) loc[base + 2] = excl; excl += v2;
    if (base + 3 < N) loc[base + 3] = excl;
}

__global__ void scan_b(int* __restrict__ bsum, int nb) {
    if (threadIdx.x == 0 && blockIdx.x == 0) {
        int run = 0;
        for (int i = 0; i < nb; ++i) { int v = bsum[i]; bsum[i] = run; run += v; }
    }
}

__global__ void scan_c(const int* __restrict__ loc, const int* __restrict__ bsum,
                       int* __restrict__ rs, int* __restrict__ cursor, int N, int E) {
    int i = blockIdx.x * 256 + threadIdx.x;
    if (i < N) {
        int v = loc[i] + bsum[i >> 10];
        rs[i] = v; cursor[i] = v;
    }
    if (i == 0) rs[N] = E;
}

// store edge -> CSR slot (perm), not slot -> edge
__global__ void scatter_k(const int* __restrict__ ei, const int* __restrict__ flag,
                          int* __restrict__ cursor, int* __restrict__ perm, int E) {
    int e = blockIdx.x * 256 + threadIdx.x;
    if (e >= E) return;
    int dst = (*flag == 0) ? ei[2 * (E + e)] : ei[E + e];
    int pos = atomicAdd(&cursor[dst], 1);
    perm[e] = pos;
}

// ---------------- main edge kernel ----------------
// Single LDS buffer Sb holds X (L1 input), then H (L1/L2 output), then EO staging.
// TE=64 / 256 threads / 4 waves, 4 blocks/CU (39.9KB LDS): proven best config.
// Phase A (prep, cols 256..287) and Phase B (s-gather, cols 0..255) share one
// barrier region (B re-reads ei, L1-hot).
// SWAPPED-OPERAND MFMA: acc = mfma(W_frag, X_frag) -> D = H^T, so each lane
// owns edge=l15 and 4 CONSECUTIVE features -> epilogue writes are bf16x4 (8B)
// instead of 4 scalar u16 (4x fewer LDS writes, ~2-way banks).

template<int CSR>
__launch_bounds__(256, 4)
__global__ void edge_kernel(const __bf16* __restrict__ s16,
                            const float* __restrict__ pos,
                            const int* __restrict__ ei,
                            const float* __restrict__ b1, const float* __restrict__ b2,
                            const float* __restrict__ bsm, const float* __restrict__ bvm,
                            const float* __restrict__ centers, const float* __restrict__ widths,
                            const __bf16* __restrict__ W1t, const __bf16* __restrict__ W2t,
                            const __bf16* __restrict__ W3t,
                            const int* __restrict__ flag,
                            const int* __restrict__ perm,
                            __bf16* __restrict__ EO,
                            float* __restrict__ dirx, float* __restrict__ diry,
                            float* __restrict__ dirz,
                            float* __restrict__ out, int N, int E) {
    __shared__ __align__(16) __bf16 Sb[TE][XS];
    __shared__ float sdir[3][TE];
    __shared__ int ssrc[TE], sdst[TE], svalid[TE], sperm[TE];

    const int t    = threadIdx.x;
    const int lane = t & 63;
    const int wave = t >> 6;
    const int e0   = blockIdx.x * TE;
    const int i64  = (*flag == 0);

    // ---- Phase B: gather s16[src]/s16[dst] -> X cols 0..255 (bf16, 16B/lane)
    {
        const int pair = lane >> 5;        // which of 2 edges this iter
        const int half = (lane >> 4) & 1;  // 0: src, 1: dst
        const int q    = lane & 15;        // 16-byte chunk
        const bf16x8* s8 = (const bf16x8*)s16;
#pragma unroll
        for (int i = 0; i < 8; ++i) {
            int eL = wave * 16 + i * 2 + pair;
            int e = e0 + eL;
            int ec = (e < E) ? e : 0;
            int idx = half ? (E + ec) : ec;
            int node = i64 ? ei[2 * idx] : ei[idx];
            bf16x8 x = s8[node * 16 + q];
            *(bf16x8*)&Sb[eL][half * FDIM + q * 8] = x;
        }
    }

    // ---- Phase A: per-edge prep, 4 threads per edge (cols 256..287 + side arrays)
    {
        const int eL  = t >> 2;      // 0..63 local edge
        const int sub = t & 3;       // 0..3 RBF slice
        int e = e0 + eL;
        int valid = (e < E);
        int srcn = 0, dstn = 0;
        if (valid) {
            if (i64) { srcn = ei[2 * e]; dstn = ei[2 * (E + e)]; }
            else     { srcn = ei[e];     dstn = ei[E + e]; }
        }
        float rx = pos[dstn * 3 + 0] - pos[srcn * 3 + 0];
        float ry = pos[dstn * 3 + 1] - pos[srcn * 3 + 1];
        float rz = pos[dstn * 3 + 2] - pos[srcn * 3 + 2];
        float dist = sqrtf(rx * rx + ry * ry + rz * rz);
        if (sub == 0) {
            ssrc[eL] = srcn; sdst[eL] = dstn; svalid[eL] = valid;
            float inv = dist > 0.f ? 1.f / dist : 0.f;
            float dx = rx * inv, dy = ry * inv, dz = rz * inv;
            sdir[0][eL] = dx; sdir[1][eL] = dy; sdir[2][eL] = dz;
            int p = 0;
            if (CSR && valid) {
                p = perm[e];
                __builtin_nontemporal_store(dx, &dirx[p]);
                __builtin_nontemporal_store(dy, &diry[p]);
                __builtin_nontemporal_store(dz, &dirz[p]);
            }
            sperm[eL] = p;
        }
        bf16x8 rbf;
#pragma unroll
        for (int k8 = 0; k8 < 8; ++k8) {
            int k = sub * 8 + k8;
            float val = 0.f;
            if (k < NRBF_) {
                float u = (dist - centers[k]) / (widths[k] + 1e-8f);
                val = __expf(-u * u);
            }
            rbf[k8] = (__bf16)val;
        }
        *(bf16x8*)&Sb[eL][TWOF + sub * 8] = rbf;   // 16B-aligned (592=37*16, 512+16*sub)
    }
    __syncthreads();

    const int l15 = lane & 15;
    const int hi  = lane >> 4;          // 0..3
    const int kg  = hi * 8;
    const int nbase = wave * 64;

    f32x4 acc[4][4];

    // ================= Layer 1: K=288 (reads X) =================
#pragma unroll
    for (int et = 0; et < 4; ++et)
#pragma unroll
        for (int nt = 0; nt < 4; ++nt) acc[et][nt] = (f32x4)0.f;
    {
        const __bf16* bp[4];
#pragma unroll
        for (int nt = 0; nt < 4; ++nt)
            bp[nt] = &W1t[(size_t)(nbase + nt * 16 + l15) * K1PAD + kg];
        bf16x8 bcur[4];
#pragma unroll
        for (int nt = 0; nt < 4; ++nt) bcur[nt] = *(const bf16x8*)bp[nt];
        __builtin_amdgcn_s_setprio(1);
#pragma unroll
        for (int kc = 0; kc < K1PAD; kc += 32) {
            bf16x8 bnxt[4];
            if (kc + 32 < K1PAD) {
#pragma unroll
                for (int nt = 0; nt < 4; ++nt)
                    bnxt[nt] = *(const bf16x8*)(bp[nt] + kc + 32);
            }
            bf16x8 a[4];
#pragma unroll
            for (int et = 0; et < 4; ++et)
                a[et] = *(const bf16x8*)&Sb[et * 16 + l15][kc + kg];
#pragma unroll
            for (int nt = 0; nt < 4; ++nt)
#pragma unroll
                for (int et = 0; et < 4; ++et)
                    acc[et][nt] = __builtin_amdgcn_mfma_f32_16x16x32_bf16(bcur[nt], a[et], acc[et][nt], 0, 0, 0);
#pragma unroll
            for (int nt = 0; nt < 4; ++nt) bcur[nt] = bnxt[nt];
        }
        __builtin_amdgcn_s_setprio(0);
    }
    __syncthreads();   // all X reads complete before H overwrites the buffer
    // epilogue: lane owns edge=et*16+l15, features f0..f0+3 (transposed D)
#pragma unroll
    for (int nt = 0; nt < 4; ++nt) {
        int f0 = nbase + nt * 16 + hi * 4;
        f32x4 bb = *(const f32x4*)&b1[f0];
#pragma unroll
        for (int et = 0; et < 4; ++et) {
            int edge = et * 16 + l15;
            bf16x4 pk;
#pragma unroll
            for (int r = 0; r < 4; ++r)
                pk[r] = (__bf16)silu_f(acc[et][nt][r] + bb[r]);
            *(bf16x4*)&Sb[edge][f0] = pk;
        }
    }
    __syncthreads();

    // ================= Layer 2: K=256 (reads H, rewrites H) =================
#pragma unroll
    for (int et = 0; et < 4; ++et)
#pragma unroll
        for (int nt = 0; nt < 4; ++nt) acc[et][nt] = (f32x4)0.f;
    {
        const __bf16* bp[4];
#pragma unroll
        for (int nt = 0; nt < 4; ++nt)
            bp[nt] = &W2t[(size_t)(nbase + nt * 16 + l15) * TWOF + kg];
        bf16x8 bcur[4];
#pragma unroll
        for (int nt = 0; nt < 4; ++nt) bcur[nt] = *(const bf16x8*)bp[nt];
        __builtin_amdgcn_s_setprio(1);
#pragma unroll
        for (int kc = 0; kc < TWOF; kc += 32) {
            bf16x8 bnxt[4];
            if (kc + 32 < TWOF) {
#pragma unroll
                for (int nt = 0; nt < 4; ++nt)
                    bnxt[nt] = *(const bf16x8*)(bp[nt] + kc + 32);
            }
            bf16x8 a[4];
#pragma unroll
            for (int et = 0; et < 4; ++et)
                a[et] = *(const bf16x8*)&Sb[et * 16 + l15][kc + kg];
#pragma unroll
            for (int nt = 0; nt < 4; ++nt)
#pragma unroll
                for (int et = 0; et < 4; ++et)
                    acc[et][nt] = __builtin_amdgcn_mfma_f32_16x16x32_bf16(bcur[nt], a[et], acc[et][nt], 0, 0, 0);
#pragma unroll
            for (int nt = 0; nt < 4; ++nt) bcur[nt] = bnxt[nt];
        }
        __builtin_amdgcn_s_setprio(0);
    }
    __syncthreads();   // all h1 reads complete before overwrite
#pragma unroll
    for (int nt = 0; nt < 4; ++nt) {
        int f0 = nbase + nt * 16 + hi * 4;
        f32x4 bb = *(const f32x4*)&b2[f0];
#pragma unroll
        for (int et = 0; et < 4; ++et) {
            int edge = et * 16 + l15;
            bf16x4 pk;
#pragma unroll
            for (int r = 0; r < 4; ++r)
                pk[r] = (__bf16)silu_f(acc[et][nt][r] + bb[r]);
            *(bf16x4*)&Sb[edge][f0] = pk;
        }
    }
    __syncthreads();

    // ================= Layer 3: K=256 (reads H) =================
#pragma unroll
    for (int et = 0; et < 4; ++et)
#pragma unroll
        for (int nt = 0; nt < 4; ++nt) acc[et][nt] = (f32x4)0.f;
    {
        const __bf16* bp[4];
#pragma unroll
        for (int nt = 0; nt < 4; ++nt) {
            int rowbase = ((nt >= 2) ? FDIM : 0) + wave * 32 + (nt & 1) * 16 + l15;
            bp[nt] = &W3t[(size_t)rowbase * TWOF + kg];
        }
        bf16x8 bcur[4];
#pragma unroll
        for (int nt = 0; nt < 4; ++nt) bcur[nt] = *(const bf16x8*)bp[nt];
        __builtin_amdgcn_s_setprio(1);
#pragma unroll
        for (int kc = 0; kc < TWOF; kc += 32) {
            bf16x8 bnxt[4];
            if (kc + 32 < TWOF) {
#pragma unroll
                for (int nt = 0; nt < 4; ++nt)
                    bnxt[nt] = *(const bf16x8*)(bp[nt] + kc + 32);
            }
            bf16x8 a[4];
#pragma unroll
            for (int et = 0; et < 4; ++et)
                a[et] = *(const bf16x8*)&Sb[et * 16 + l15][kc + kg];
#pragma unroll
            for (int nt = 0; nt < 4; ++nt)
#pragma unroll
                for (int et = 0; et < 4; ++et)
                    acc[et][nt] = __builtin_amdgcn_mfma_f32_16x16x32_bf16(bcur[nt], a[et], acc[et][nt], 0, 0, 0);
#pragma unroll
            for (int nt = 0; nt < 4; ++nt) bcur[nt] = bnxt[nt];
        }
        __builtin_amdgcn_s_setprio(0);
    }

    // transposed L3 bias: features f0..f0+3 per (nt,hi)
    f32x4 b3v[4];
#pragma unroll
    for (int nt = 0; nt < 4; ++nt) {
        int f0 = wave * 32 + (nt & 1) * 16 + hi * 4;
        b3v[nt] = (nt < 2) ? *(const f32x4*)&bsm[f0] : *(const f32x4*)&bvm[f0];
    }

    if (CSR) {
        __syncthreads();   // all H reads complete before EO staging overwrites buffer
        __bf16 (*EOs)[XS] = (__bf16(*)[XS])(&Sb[0][0]);
#pragma unroll
        for (int nt = 0; nt < 4; ++nt) {
            int col0 = ((nt >= 2) ? FDIM : 0) + wave * 32 + (nt & 1) * 16 + hi * 4;
            f32x4 bb = b3v[nt];
#pragma unroll
            for (int et = 0; et < 4; ++et) {
                int edge = et * 16 + l15;
                bf16x4 pk;
#pragma unroll
                for (int r = 0; r < 4; ++r)
                    pk[r] = (__bf16)(acc[et][nt][r] + bb[r]);
                *(bf16x4*)&EOs[edge][col0] = pk;
            }
        }
        __syncthreads();
        u32x4v* dst4 = (u32x4v*)EO;
#pragma unroll
        for (int j = 0; j < 8; ++j) {
            int flat = j * 256 + t;          // 0..2047
            int row = flat >> 5, col = flat & 31;
            if (!svalid[row]) continue;
            __builtin_nontemporal_store(*(const u32x4v*)&EOs[row][col * 8],
                                        &dst4[(size_t)sperm[row] * 32 + col]);
        }
    } else {
        float* outs = out;
        float* outv = out + (size_t)N * FDIM;
#pragma unroll
        for (int et = 0; et < 4; ++et) {
            int m = et * 16 + l15;
            if (!svalid[m]) continue;
            int dst = sdst[m];
            float dx = sdir[0][m], dy = sdir[1][m], dz = sdir[2][m];
#pragma unroll
            for (int nt = 0; nt < 4; ++nt) {
                int f0 = wave * 32 + (nt & 1) * 16 + hi * 4;
#pragma unroll
                for (int r = 0; r < 4; ++r) {
                    float val = acc[et][nt][r] + b3v[nt][r];
                    if (nt < 2) {
                        atomicAdd(&outs[dst * FDIM + f0 + r], val);
                    } else {
                        int base = dst * 3 * FDIM + f0 + r;
                        atomicAdd(&outv[base],            dx * val);
                        atomicAdd(&outv[base + FDIM],     dy * val);
                        atomicAdd(&outv[base + 2 * FDIM], dz * val);
                    }
                }
            }
        }
    }
}

// ---------------- node aggregation: fully streaming (EO/dir pre-sorted) ----------------

__launch_bounds__(256)
__global__ void node_kernel(const float* __restrict__ s, const float* __restrict__ v,
                            const __bf16* __restrict__ EO,
                            const float* __restrict__ dirx, const float* __restrict__ diry,
                            const float* __restrict__ dirz,
                            const int* __restrict__ rs,
                            float* __restrict__ out, int N) {
    int wave = threadIdx.x >> 6, lane = threadIdx.x & 63;
    int n = blockIdx.x * 4 + wave;
    if (n >= N) return;
    int beg = rs[n], end = rs[n + 1];

    float a0 = 0.f, a1 = 0.f;
    float vx0 = 0.f, vx1 = 0.f, vy0 = 0.f, vy1 = 0.f, vz0 = 0.f, vz1 = 0.f;
    const unsigned* EO32 = (const unsigned*)EO;

#pragma unroll 2
    for (int i = beg; i < end; ++i) {
        unsigned pds = __builtin_nontemporal_load(&EO32[(size_t)i * 128 + lane]);
        unsigned pvm = __builtin_nontemporal_load(&EO32[(size_t)i * 128 + 64 + lane]);
        float dx = __builtin_nontemporal_load(&dirx[i]);
        float dy = __builtin_nontemporal_load(&diry[i]);
        float dz = __builtin_nontemporal_load(&dirz[i]);
        float d0 = blo(pds), d1 = bhi(pds);
        float m0 = blo(pvm), m1 = bhi(pvm);
        a0 += d0; a1 += d1;
        vx0 = fmaf(dx, m0, vx0); vx1 = fmaf(dx, m1, vx1);
        vy0 = fmaf(dy, m0, vy0); vy1 = fmaf(dy, m1, vy1);
        vz0 = fmaf(dz, m0, vz0); vz1 = fmaf(dz, m1, vz1);
    }

    f32x2 sv = *((const f32x2*)&s[(size_t)n * FDIM] + lane);
    f32x2 o0 = { sv.x + a0, sv.y + a1 };
    __builtin_nontemporal_store(o0, (f32x2*)&out[(size_t)n * FDIM] + lane);

    const float* vb = &v[(size_t)n * 3 * FDIM];
    float* ovb = &out[(size_t)N * FDIM + (size_t)n * 3 * FDIM];
    f32x2 vv;
    vv = *((const f32x2*)vb + lane);
    f32x2 ox = { vv.x + vx0, vv.y + vx1 };
    __builtin_nontemporal_store(ox, (f32x2*)ovb + lane);
    vv = *((const f32x2*)(vb + FDIM) + lane);
    f32x2 oy = { vv.x + vy0, vv.y + vy1 };
    __builtin_nontemporal_store(oy, (f32x2*)(ovb + FDIM) + lane);
    vv = *((const f32x2*)(vb + 2 * FDIM) + lane);
    f32x2 oz = { vv.x + vz0, vv.y + vz1 };
    __builtin_nontemporal_store(oz, (f32x2*)(ovb + 2 * FDIM) + lane);
}

// ---------------- host ----------------

static inline size_t align256(size_t x) { return (x + 255) & ~(size_t)255; }

extern "C" void kernel_launch(void* const* d_in, const int* in_sizes, int n_in,
                              void* d_out, int out_size, void* d_ws, size_t ws_size,
                              hipStream_t stream) {
    const float* s   = (const float*)d_in[0];
    const float* v   = (const float*)d_in[1];
    const float* pos = (const float*)d_in[2];
    const int*   ei  = (const int*)d_in[3];
    const float* W1  = (const float*)d_in[4];
    const float* b1  = (const float*)d_in[5];
    const float* W2  = (const float*)d_in[6];
    const float* b2  = (const float*)d_in[7];
    const float* Wsm = (const float*)d_in[8];
    const float* bsm = (const float*)d_in[9];
    const float* Wvm = (const float*)d_in[10];
    const float* bvm = (const float*)d_in[11];
    const float* centers = (const float*)d_in[12];
    const float* widths  = (const float*)d_in[13];
    float* out = (float*)d_out;

    int N = in_sizes[0] / FDIM;
    int E = in_sizes[3] / 2;
    int nblocks = (E + TE - 1) / TE;

    // workspace layout
    size_t off = 0;
    int* flag = (int*)((char*)d_ws + off);           off = align256(off + 4);
    __bf16* W1t = (__bf16*)((char*)d_ws + off);      off = align256(off + (size_t)256 * K1PAD * 2);
    __bf16* W2t = (__bf16*)((char*)d_ws + off);      off = align256(off + (size_t)256 * TWOF * 2);
    __bf16* W3t = (__bf16*)((char*)d_ws + off);      off = align256(off + (size_t)256 * TWOF * 2);
    __bf16* s16 = (__bf16*)((char*)d_ws + off);      off = align256(off + (size_t)N * FDIM * 2);
    int* hist   = (int*)((char*)d_ws + off);         off = align256(off + (size_t)N * 4);
    int* loc    = (int*)((char*)d_ws + off);         off = align256(off + (size_t)N * 4);
    int* bsum   = (int*)((char*)d_ws + off);         off = align256(off + 1024);
    int* rs     = (int*)((char*)d_ws + off);         off = align256(off + (size_t)(N + 1) * 4);
    int* cursor = (int*)((char*)d_ws + off);         off = align256(off + (size_t)N * 4);
    int* perm   = (int*)((char*)d_ws + off);         off = align256(off + (size_t)E * 4);
    float* dirx = (float*)((char*)d_ws + off);       off = align256(off + (size_t)E * 4);
    float* diry = (float*)((char*)d_ws + off);       off = align256(off + (size_t)E * 4);
    float* dirz = (float*)((char*)d_ws + off);       off = align256(off + (size_t)E * 4);
    __bf16* EO  = (__bf16*)((char*)d_ws + off);      off = align256(off + (size_t)E * 256 * 2);
    bool use_csr = (off <= ws_size);

    int nsample = E < 1024 ? E : 1024;
    hipLaunchKernelGGL(sniff_idx, dim3(1), dim3(256), 0, stream, ei, nsample, flag);

    int n8 = (N * FDIM) / 8;
    int nprep = 256 * K1PAD + 131072 + n8 + N;
    hipLaunchKernelGGL(prep_all, dim3((nprep + 255) / 256), dim3(256), 0, stream,
                       W1, W2, Wsm, Wvm, W1t, W2t, W3t,
                       (const float4*)s, (bf16x8*)s16, n8, hist, N);

    if (use_csr) {
        int nb = (N + 1023) / 1024;
        hipLaunchKernelGGL(hist_k, dim3((E + 255) / 256), dim3(256), 0, stream, ei, flag, hist, E);
        hipLaunchKernelGGL(scan_a, dim3(nb), dim3(256), 0, stream, hist, loc, bsum, N);
        hipLaunchKernelGGL(scan_b, dim3(1), dim3(64), 0, stream, bsum, nb);
        hipLaunchKernelGGL(scan_c, dim3((N + 255) / 256), dim3(256), 0, stream, loc, bsum, rs, cursor, N, E);
        hipLaunchKernelGGL(scatter_k, dim3((E + 255) / 256), dim3(256), 0, stream, ei, flag, cursor, perm, E);

        hipLaunchKernelGGL(edge_kernel<1>, dim3(nblocks), dim3(256), 0, stream,
                           s16, pos, ei, b1, b2, bsm, bvm, centers, widths,
                           W1t, W2t, W3t, flag, perm, EO, dirx, diry, dirz, out, N, E);

        hipLaunchKernelGGL(node_kernel, dim3((N + 3) / 4), dim3(256), 0, stream,
                           s, v, EO, dirx, diry, dirz, rs, out, N);
    } else {
        int nf4    = (N * FDIM) / 4;
        int total4 = N * FDIM;
        hipLaunchKernelGGL(init_out, dim3(8192), dim3(256), 0, stream,
                           (const float4*)s, (const float4*)v, (float4*)out, nf4, total4);
        hipLaunchKernelGGL(edge_kernel<0>, dim3(nblocks), dim3(256), 0, stream,
                           s16, pos, ei, b1, b2, bsm, bvm, centers, widths,
                           W1t, W2t, W3t, flag, perm, EO, dirx, diry, dirz, out, N, E);
    }
}